// Round 6
// baseline (241.593 us; speedup 1.0000x reference)
//
#include <hip/hip_runtime.h>
#include <stdint.h>

typedef __attribute__((ext_vector_type(8))) short short8;
typedef __attribute__((ext_vector_type(4))) float floatx4;

__device__ __forceinline__ float b2f(unsigned short u) {
    union { unsigned int i; float f; } x; x.i = ((unsigned int)u) << 16; return x.f;
}
__device__ __forceinline__ unsigned short f2b(float f) {
    unsigned int x = __float_as_uint(f);
    return (unsigned short)((x + 0x7FFFu + ((x >> 16) & 1u)) >> 16);
}
__device__ __forceinline__ unsigned int cvt_pk_bf16(float lo, float hi) {
    unsigned int r;
    asm("v_cvt_pk_bf16_f32 %0, %1, %2" : "=v"(r) : "v"(lo), "v"(hi));
    return r;
}
__device__ __forceinline__ float exp2_(float x) {
    float r;
    asm("v_exp_f32 %0, %1" : "=v"(r) : "v"(x));
    return r;
}

__device__ __forceinline__ float ldf(const float* p) { return *p; }
__device__ __forceinline__ float ldf(const unsigned short* p) { return b2f(*p); }

__device__ __forceinline__ void gload_lds16(const void* g, void* l) {
    __builtin_amdgcn_global_load_lds((const __attribute__((address_space(1))) unsigned int*)g,
                                     (__attribute__((address_space(3))) unsigned int*)l, 16, 0, 0);
}

// ---------------- cast f32 -> bf16 ----------------
__global__ void cast_kernel(const float* __restrict__ in, unsigned short* __restrict__ out, int n) {
    int i = (blockIdx.x * blockDim.x + threadIdx.x) * 4;
    if (i + 3 < n) {
        float4 v = *reinterpret_cast<const float4*>(in + i);
        out[i + 0] = f2b(v.x);
        out[i + 1] = f2b(v.y);
        out[i + 2] = f2b(v.z);
        out[i + 3] = f2b(v.w);
    }
}

// ---------------- transpose: out[c][r] = in[r][c], bf16 out, strided ----------------
template<typename T>
__global__ void transpose_to_bf16(const T* __restrict__ in, unsigned short* __restrict__ out,
                                  int ld_in, int ld_out) {
    __shared__ float tile[64][65];
    int tx = threadIdx.x & 63, ty = threadIdx.x >> 6;
    int c0 = blockIdx.x * 64, r0 = blockIdx.y * 64;
    #pragma unroll
    for (int i = 0; i < 64; i += 4)
        tile[ty + i][tx] = ldf(&in[(size_t)(r0 + ty + i) * ld_in + c0 + tx]);
    __syncthreads();
    #pragma unroll
    for (int i = 0; i < 64; i += 4)
        out[(size_t)(c0 + ty + i) * ld_out + r0 + tx] = f2b(tile[tx][ty + i]);
}

// ---------------- GEMM v2: C[M][N] = A[M][K] @ BT[N][K]^T ----------------
// 64(M)x128(N) tile, BK=64, 4 waves. Swizzled LDS, double-buffered, counted vmcnt(6),
// bijective XCD grid swizzle (nwg % 8 == 0).
template<int OF32>
__global__ __launch_bounds__(256)
void gemm64x128(const unsigned short* __restrict__ A, const unsigned short* __restrict__ BT,
                void* __restrict__ Cout, int M, int N, int K) {
    __shared__ __align__(16) unsigned short As[2][64 * 64];
    __shared__ __align__(16) unsigned short Bs[2][128 * 64];
    int tid = threadIdx.x;
    int l = tid & 63, w = tid >> 6;
    int lr = l & 15, lg = l >> 4;

    int gx = gridDim.x;
    int nwg = gx * gridDim.y;
    int flat = blockIdx.y * gx + blockIdx.x;
    int q8 = nwg >> 3;
    int f2 = (flat & 7) * q8 + (flat >> 3);
    int bx = f2 % gx, by = f2 / gx;
    int nb = bx * 128, mb = by * 64;

    floatx4 acc[4][2];
    #pragma unroll
    for (int m = 0; m < 4; ++m)
        #pragma unroll
        for (int f = 0; f < 2; ++f) acc[m][f] = (floatx4)(0.f);

    int ca1 = tid + 256;
    int ra0 = tid >> 3, ja0 = (tid & 7) ^ (ra0 & 7);
    int ra1 = ca1 >> 3, ja1 = (ca1 & 7) ^ (ra1 & 7);
    const unsigned short* Ag0 = A + (size_t)(mb + ra0) * K + ja0 * 8;
    const unsigned short* Ag1 = A + (size_t)(mb + ra1) * K + ja1 * 8;
    const unsigned short* Bg[4];
    #pragma unroll
    for (int i = 0; i < 4; ++i) {
        int c = tid + 256 * i;
        int r = c >> 3, j = (c & 7) ^ (r & 7);
        Bg[i] = BT + (size_t)(nb + r) * K + j * 8;
    }

    auto stage = [&](int buf, int kb) {
        gload_lds16(Ag0 + kb, &As[buf][tid * 8]);
        gload_lds16(Ag1 + kb, &As[buf][ca1 * 8]);
        #pragma unroll
        for (int i = 0; i < 4; ++i)
            gload_lds16(Bg[i] + kb, &Bs[buf][(tid + 256 * i) * 8]);
    };

    int nsteps = K >> 6;
    stage(0, 0);
    for (int it = 0; it < nsteps; ++it) {
        int nxt = (it + 1 < nsteps) ? it + 1 : it;
        stage((it + 1) & 1, nxt * 64);
        asm volatile("s_waitcnt vmcnt(6)" ::: "memory");
        __builtin_amdgcn_s_barrier();
        __builtin_amdgcn_sched_barrier(0);

        const unsigned short* Ab = As[it & 1];
        const unsigned short* Bb = Bs[it & 1];
        #pragma unroll
        for (int kh = 0; kh < 2; ++kh) {
            int sl = ((kh * 4 + lg) ^ (lr & 7)) * 8;
            short8 af[4], bf[2];
            #pragma unroll
            for (int m = 0; m < 4; ++m)
                af[m] = *reinterpret_cast<const short8*>(Ab + (m * 16 + lr) * 64 + sl);
            #pragma unroll
            for (int f = 0; f < 2; ++f)
                bf[f] = *reinterpret_cast<const short8*>(Bb + (w * 32 + f * 16 + lr) * 64 + sl);
            #pragma unroll
            for (int m = 0; m < 4; ++m)
                #pragma unroll
                for (int f = 0; f < 2; ++f)
                    acc[m][f] = __builtin_amdgcn_mfma_f32_16x16x32_bf16(af[m], bf[f], acc[m][f], 0, 0, 0);
        }
        __builtin_amdgcn_sched_barrier(0);
        __builtin_amdgcn_s_barrier();
    }
    asm volatile("s_waitcnt vmcnt(0)" ::: "memory");

    #pragma unroll
    for (int m = 0; m < 4; ++m) {
        int orow = mb + m * 16 + lg * 4;
        #pragma unroll
        for (int f = 0; f < 2; ++f) {
            int ocol = nb + w * 32 + f * 16 + lr;
            #pragma unroll
            for (int r = 0; r < 4; ++r) {
                if (OF32)
                    ((float*)Cout)[(size_t)(orow + r) * N + ocol] = acc[m][f][r];
                else
                    ((unsigned short*)Cout)[(size_t)(orow + r) * N + ocol] = f2b(acc[m][f][r]);
            }
        }
    }
}

// ---------------- RoPE in-place ----------------
__global__ void rope_kernel(unsigned short* __restrict__ x, const int* __restrict__ pos_ids,
                            int H, int stride, float scale) {
    int idx = blockIdx.x * blockDim.x + threadIdx.x;
    int i = idx & 31;
    int h = (idx >> 5) % H;
    int s = idx / (32 * H);
    unsigned short* p = x + (size_t)s * stride + h * 64;
    float x1 = b2f(p[i]), x2 = b2f(p[i + 32]);
    float pos = (float)pos_ids[s];
    float inv = exp2f(-0.41524101186092029f * (float)i);
    float a = pos * inv;
    float sn, cs;
    __sincosf(a, &sn, &cs);
    p[i]      = f2b((x1 * cs - x2 * sn) * scale);
    p[i + 32] = f2b((x2 * cs + x1 * sn) * scale);
}

// ---------------- causal GQA flash attention v6: barrier-free, register-direct ----------------
// 4096 independent waves (1024 blocks x 4 waves), heavy q-tiles dispatched first (LPT).
// 1 wave = 16 q-rows (q = qt*16 + lr). 64-key tiles. K/V read straight from L1/L2 into
// registers (all waves of a block read identical K/V addresses -> L1 hit). No LDS, no
// barriers -> waves slip freely; 4 waves/SIMD hide load + shuffle latency.
// Softmax in exp2 domain (Q pre-scaled by log2e/8); defer-max THR=11.5; setprio on MFMA.
__global__ __launch_bounds__(256, 4)
void attn_kernel(const unsigned short* __restrict__ QKV, // [2048][3072] bf16 (q|k|v)
                 const unsigned short* __restrict__ VT,  // [512][2048]  bf16
                 unsigned short* __restrict__ O) {       // [2048][2048] bf16
    const int S = 2048, LDQ = 3072, HID = 2048;
    int l = threadIdx.x & 63, w = threadIdx.x >> 6;
    int b = blockIdx.x;
    int h = b & 31;
    int qtg = 31 - (b >> 5);        // heavy groups dispatched first
    int qt = qtg * 4 + w;
    int lr = l & 15, g = l >> 4;
    int kvh = h >> 2;
    int q = qt * 16 + lr;

    const unsigned short* Qrow = QKV + (size_t)q * LDQ + h * 64;
    short8 qf0 = *reinterpret_cast<const short8*>(Qrow + g * 8);
    short8 qf1 = *reinterpret_cast<const short8*>(Qrow + 32 + g * 8);

    // K row pointers (advance 64 keys per tile); V^T col pointers (advance 64 per tile)
    const unsigned short* kp[4];
    const unsigned short* vp[4];
    #pragma unroll
    for (int t = 0; t < 4; ++t)
        kp[t] = QKV + 2048 + (size_t)kvh * 64 + (size_t)(t * 16 + lr) * LDQ + g * 8;
    #pragma unroll
    for (int db = 0; db < 4; ++db)
        vp[db] = VT + (size_t)(kvh * 64 + db * 16 + lr) * S + g * 8;

    floatx4 acc[4];
    #pragma unroll
    for (int db = 0; db < 4; ++db) acc[db] = (floatx4)(0.f);
    float m_run = -1e30f, l_run = 0.f;

    int src0 = lr + (g & 1) * 32;
    int src1 = src0 + 16;
    bool hi_t = (g >> 1) != 0;

    int nfull = qt >> 2;
    for (int kt = 0; kt <= nfull; ++kt) {
        // K fragments -> registers (L1-resident: shared across the block's waves)
        short8 kf0[4], kf1[4];
        #pragma unroll
        for (int t = 0; t < 4; ++t) {
            kf0[t] = *reinterpret_cast<const short8*>(kp[t]);
            kf1[t] = *reinterpret_cast<const short8*>(kp[t] + 32);
            kp[t] += (size_t)64 * LDQ;
        }
        __builtin_amdgcn_s_setprio(1);
        floatx4 st[4];
        #pragma unroll
        for (int t = 0; t < 4; ++t) {
            floatx4 z = (floatx4)(0.f);
            z = __builtin_amdgcn_mfma_f32_16x16x32_bf16(kf0[t], qf0, z, 0, 0, 0);
            st[t] = __builtin_amdgcn_mfma_f32_16x16x32_bf16(kf1[t], qf1, z, 0, 0, 0);
        }
        __builtin_amdgcn_s_setprio(0);

        // V fragments issued now; softmax below hides their latency
        short8 vf0[4], vf1[4];
        #pragma unroll
        for (int db = 0; db < 4; ++db) {
            vf0[db] = *reinterpret_cast<const short8*>(vp[db]);
            vf1[db] = *reinterpret_cast<const short8*>(vp[db] + 32);
            vp[db] += 64;
        }

        if (kt == nfull) {
            #pragma unroll
            for (int t = 0; t < 4; ++t)
                #pragma unroll
                for (int r = 0; r < 4; ++r)
                    if (kt * 64 + t * 16 + g * 4 + r > q) st[t][r] = -1e30f;
        }

        // online softmax (exp2 domain, defer-max)
        float tt[4];
        #pragma unroll
        for (int t = 0; t < 4; ++t)
            tt[t] = fmaxf(fmaxf(st[t][0], st[t][1]), fmaxf(st[t][2], st[t][3]));
        float tm = fmaxf(fmaxf(tt[0], tt[1]), fmaxf(tt[2], tt[3]));
        tm = fmaxf(tm, __shfl_xor(tm, 16));
        tm = fmaxf(tm, __shfl_xor(tm, 32));
        if (!__all(tm <= m_run + 11.5f)) {
            float mn = fmaxf(m_run, tm);
            float al = exp2_(m_run - mn);
            l_run *= al;
            #pragma unroll
            for (int db = 0; db < 4; ++db) acc[db] *= al;
            m_run = mn;
        }
        unsigned int ulo[4], uhi[4];
        float rs = 0.f;
        #pragma unroll
        for (int t = 0; t < 4; ++t) {
            float e0 = exp2_(st[t][0] - m_run), e1 = exp2_(st[t][1] - m_run);
            float e2 = exp2_(st[t][2] - m_run), e3 = exp2_(st[t][3] - m_run);
            rs += (e0 + e1) + (e2 + e3);
            ulo[t] = cvt_pk_bf16(e0, e1);
            uhi[t] = cvt_pk_bf16(e2, e3);
        }
        rs += __shfl_xor(rs, 16);
        rs += __shfl_xor(rs, 32);
        l_run += rs;

        // PV: two 32-key steps
        #pragma unroll
        for (int ks = 0; ks < 2; ++ks) {
            unsigned int a0 = __shfl((int)ulo[ks * 2], src0), b0 = __shfl((int)ulo[ks * 2 + 1], src0);
            unsigned int a1 = __shfl((int)uhi[ks * 2], src0), b1 = __shfl((int)uhi[ks * 2 + 1], src0);
            unsigned int a2 = __shfl((int)ulo[ks * 2], src1), b2 = __shfl((int)ulo[ks * 2 + 1], src1);
            unsigned int a3 = __shfl((int)uhi[ks * 2], src1), b3 = __shfl((int)uhi[ks * 2 + 1], src1);
            union { unsigned int u[4]; short8 s; } pf;
            pf.u[0] = hi_t ? b0 : a0;
            pf.u[1] = hi_t ? b1 : a1;
            pf.u[2] = hi_t ? b2 : a2;
            pf.u[3] = hi_t ? b3 : a3;
            __builtin_amdgcn_s_setprio(1);
            #pragma unroll
            for (int db = 0; db < 4; ++db) {
                short8 vf = (ks == 0) ? vf0[db] : vf1[db];
                acc[db] = __builtin_amdgcn_mfma_f32_16x16x32_bf16(vf, pf.s, acc[db], 0, 0, 0);
            }
            __builtin_amdgcn_s_setprio(0);
        }
    }

    float inv = 1.0f / l_run;
    unsigned short* Op = O + (size_t)q * HID + h * 64;
    #pragma unroll
    for (int db = 0; db < 4; ++db) {
        int d0 = db * 16 + g * 4;
        *reinterpret_cast<unsigned int*>(Op + d0)     = cvt_pk_bf16(acc[db][0] * inv, acc[db][1] * inv);
        *reinterpret_cast<unsigned int*>(Op + d0 + 2) = cvt_pk_bf16(acc[db][2] * inv, acc[db][3] * inv);
    }
}

extern "C" void kernel_launch(void* const* d_in, const int* in_sizes, int n_in,
                              void* d_out, int out_size, void* d_ws, size_t ws_size,
                              hipStream_t stream) {
    const int S = 2048, HID = 2048, KVD = 512, NQKV = 3072;
    const float* hs = (const float*)d_in[0];
    const float* Wq = (const float*)d_in[1];
    const float* Wk = (const float*)d_in[2];
    const float* Wv = (const float*)d_in[3];
    const float* Wo = (const float*)d_in[4];
    const int* pos  = (const int*)d_in[5];

    char* base = (char*)d_ws;
    auto alloc = [&](size_t bytes) {
        char* r = base;
        base += (bytes + 255) & ~(size_t)255;
        return r;
    };
    unsigned short* hs_b     = (unsigned short*)alloc((size_t)S * HID * 2);
    unsigned short* Wqkv     = (unsigned short*)alloc((size_t)NQKV * HID * 2);
    unsigned short* WoT      = (unsigned short*)alloc((size_t)HID * HID * 2);
    unsigned short* qkv      = (unsigned short*)alloc((size_t)S * NQKV * 2);
    unsigned short* vT       = (unsigned short*)alloc((size_t)KVD * S * 2);
    unsigned short* attn_out = (unsigned short*)alloc((size_t)S * HID * 2);

    cast_kernel<<<(S * HID / 4 + 255) / 256, 256, 0, stream>>>(hs, hs_b, S * HID);

    transpose_to_bf16<float><<<dim3(HID / 64, HID / 64), 256, 0, stream>>>(Wq, Wqkv, HID, HID);
    transpose_to_bf16<float><<<dim3(KVD / 64, HID / 64), 256, 0, stream>>>(Wk, Wqkv + (size_t)2048 * HID, KVD, HID);
    transpose_to_bf16<float><<<dim3(KVD / 64, HID / 64), 256, 0, stream>>>(Wv, Wqkv + (size_t)2560 * HID, KVD, HID);
    transpose_to_bf16<float><<<dim3(HID / 64, HID / 64), 256, 0, stream>>>(Wo, WoT, HID, HID);

    // fused QKV projection: grid 24x32 = 768 blocks (%8==0)
    gemm64x128<0><<<dim3(NQKV / 128, S / 64), 256, 0, stream>>>(hs_b, Wqkv, qkv, S, NQKV, HID);

    // Q scaled by (1/8)*log2(e) -> softmax runs in exp2 domain
    rope_kernel<<<(S * 32 * 32) / 256, 256, 0, stream>>>(qkv, pos, 32, NQKV, 0.18033688011112042f);
    rope_kernel<<<(S * 8 * 32) / 256, 256, 0, stream>>>(qkv + 2048, pos, 8, NQKV, 1.0f);

    transpose_to_bf16<unsigned short><<<dim3(KVD / 64, S / 64), 256, 0, stream>>>(qkv + 2560, vT, NQKV, S);

    // attention: 1024 blocks x 4 independent waves, heavy q-tiles first (LPT greedy)
    attn_kernel<<<1024, 256, 0, stream>>>(qkv, vT, attn_out);

    // output projection: grid 16x32 = 512 blocks (%8==0)
    gemm64x128<1><<<dim3(HID / 128, S / 64), 256, 0, stream>>>(attn_out, WoT, (float*)d_out, S, HID, HID);
}

// Round 9
// 148.813 us; speedup vs baseline: 1.6235x; 1.6235x over previous
//
#include <hip/hip_runtime.h>
#include <stdint.h>

typedef __attribute__((ext_vector_type(8))) short short8;
typedef __attribute__((ext_vector_type(4))) float floatx4;
typedef __attribute__((ext_vector_type(16))) float floatx16;

__device__ __forceinline__ float b2f(unsigned short u) {
    union { unsigned int i; float f; } x; x.i = ((unsigned int)u) << 16; return x.f;
}
__device__ __forceinline__ unsigned short f2b(float f) {
    unsigned int x = __float_as_uint(f);
    return (unsigned short)((x + 0x7FFFu + ((x >> 16) & 1u)) >> 16);
}
__device__ __forceinline__ unsigned int cvt_pk_bf16(float lo, float hi) {
    unsigned int r;
    asm("v_cvt_pk_bf16_f32 %0, %1, %2" : "=v"(r) : "v"(lo), "v"(hi));
    return r;
}
__device__ __forceinline__ float exp2_(float x) {
    float r;
    asm("v_exp_f32 %0, %1" : "=v"(r) : "v"(x));
    return r;
}

__device__ __forceinline__ float ldf(const float* p) { return *p; }
__device__ __forceinline__ float ldf(const unsigned short* p) { return b2f(*p); }

__device__ __forceinline__ void gload_lds16(const void* g, void* l) {
    __builtin_amdgcn_global_load_lds((const __attribute__((address_space(1))) unsigned int*)g,
                                     (__attribute__((address_space(3))) unsigned int*)l, 16, 0, 0);
}

// ---------------- cast f32 -> bf16 ----------------
__global__ void cast_kernel(const float* __restrict__ in, unsigned short* __restrict__ out, int n) {
    int i = (blockIdx.x * blockDim.x + threadIdx.x) * 4;
    if (i + 3 < n) {
        float4 v = *reinterpret_cast<const float4*>(in + i);
        out[i + 0] = f2b(v.x);
        out[i + 1] = f2b(v.y);
        out[i + 2] = f2b(v.z);
        out[i + 3] = f2b(v.w);
    }
}

// ---------------- transpose: out[c][r] = in[r][c], bf16 out, strided ----------------
template<typename T>
__global__ void transpose_to_bf16(const T* __restrict__ in, unsigned short* __restrict__ out,
                                  int ld_in, int ld_out) {
    __shared__ float tile[64][65];
    int tx = threadIdx.x & 63, ty = threadIdx.x >> 6;
    int c0 = blockIdx.x * 64, r0 = blockIdx.y * 64;
    #pragma unroll
    for (int i = 0; i < 64; i += 4)
        tile[ty + i][tx] = ldf(&in[(size_t)(r0 + ty + i) * ld_in + c0 + tx]);
    __syncthreads();
    #pragma unroll
    for (int i = 0; i < 64; i += 4)
        out[(size_t)(c0 + ty + i) * ld_out + r0 + tx] = f2b(tile[tx][ty + i]);
}

// ---------------- GEMM v2 (round-5, proven): 64x128 tile, BK=64, swizzled LDS ----------------
template<int OF32>
__global__ __launch_bounds__(256)
void gemm64x128(const unsigned short* __restrict__ A, const unsigned short* __restrict__ BT,
                void* __restrict__ Cout, int M, int N, int K) {
    __shared__ __align__(16) unsigned short As[2][64 * 64];
    __shared__ __align__(16) unsigned short Bs[2][128 * 64];
    int tid = threadIdx.x;
    int l = tid & 63, w = tid >> 6;
    int lr = l & 15, lg = l >> 4;

    int gx = gridDim.x;
    int nwg = gx * gridDim.y;
    int flat = blockIdx.y * gx + blockIdx.x;
    int q8 = nwg >> 3;
    int f2 = (flat & 7) * q8 + (flat >> 3);
    int bx = f2 % gx, by = f2 / gx;
    int nb = bx * 128, mb = by * 64;

    floatx4 acc[4][2];
    #pragma unroll
    for (int m = 0; m < 4; ++m)
        #pragma unroll
        for (int f = 0; f < 2; ++f) acc[m][f] = (floatx4)(0.f);

    int ca1 = tid + 256;
    int ra0 = tid >> 3, ja0 = (tid & 7) ^ (ra0 & 7);
    int ra1 = ca1 >> 3, ja1 = (ca1 & 7) ^ (ra1 & 7);
    const unsigned short* Ag0 = A + (size_t)(mb + ra0) * K + ja0 * 8;
    const unsigned short* Ag1 = A + (size_t)(mb + ra1) * K + ja1 * 8;
    const unsigned short* Bg[4];
    #pragma unroll
    for (int i = 0; i < 4; ++i) {
        int c = tid + 256 * i;
        int r = c >> 3, j = (c & 7) ^ (r & 7);
        Bg[i] = BT + (size_t)(nb + r) * K + j * 8;
    }

    auto stage = [&](int buf, int kb) {
        gload_lds16(Ag0 + kb, &As[buf][tid * 8]);
        gload_lds16(Ag1 + kb, &As[buf][ca1 * 8]);
        #pragma unroll
        for (int i = 0; i < 4; ++i)
            gload_lds16(Bg[i] + kb, &Bs[buf][(tid + 256 * i) * 8]);
    };

    int nsteps = K >> 6;
    stage(0, 0);
    for (int it = 0; it < nsteps; ++it) {
        int nxt = (it + 1 < nsteps) ? it + 1 : it;
        stage((it + 1) & 1, nxt * 64);
        asm volatile("s_waitcnt vmcnt(6)" ::: "memory");
        __builtin_amdgcn_s_barrier();
        __builtin_amdgcn_sched_barrier(0);

        const unsigned short* Ab = As[it & 1];
        const unsigned short* Bb = Bs[it & 1];
        #pragma unroll
        for (int kh = 0; kh < 2; ++kh) {
            int sl = ((kh * 4 + lg) ^ (lr & 7)) * 8;
            short8 af[4], bf[2];
            #pragma unroll
            for (int m = 0; m < 4; ++m)
                af[m] = *reinterpret_cast<const short8*>(Ab + (m * 16 + lr) * 64 + sl);
            #pragma unroll
            for (int f = 0; f < 2; ++f)
                bf[f] = *reinterpret_cast<const short8*>(Bb + (w * 32 + f * 16 + lr) * 64 + sl);
            #pragma unroll
            for (int m = 0; m < 4; ++m)
                #pragma unroll
                for (int f = 0; f < 2; ++f)
                    acc[m][f] = __builtin_amdgcn_mfma_f32_16x16x32_bf16(af[m], bf[f], acc[m][f], 0, 0, 0);
        }
        __builtin_amdgcn_sched_barrier(0);
        __builtin_amdgcn_s_barrier();
    }
    asm volatile("s_waitcnt vmcnt(0)" ::: "memory");

    #pragma unroll
    for (int m = 0; m < 4; ++m) {
        int orow = mb + m * 16 + lg * 4;
        #pragma unroll
        for (int f = 0; f < 2; ++f) {
            int ocol = nb + w * 32 + f * 16 + lr;
            #pragma unroll
            for (int r = 0; r < 4; ++r) {
                if (OF32)
                    ((float*)Cout)[(size_t)(orow + r) * N + ocol] = acc[m][f][r];
                else
                    ((unsigned short*)Cout)[(size_t)(orow + r) * N + ocol] = f2b(acc[m][f][r]);
            }
        }
    }
}

// ---------------- RoPE in-place ----------------
__global__ void rope_kernel(unsigned short* __restrict__ x, const int* __restrict__ pos_ids,
                            int H, int stride, float scale) {
    int idx = blockIdx.x * blockDim.x + threadIdx.x;
    int i = idx & 31;
    int h = (idx >> 5) % H;
    int s = idx / (32 * H);
    unsigned short* p = x + (size_t)s * stride + h * 64;
    float x1 = b2f(p[i]), x2 = b2f(p[i + 32]);
    float pos = (float)pos_ids[s];
    float inv = exp2f(-0.41524101186092029f * (float)i);
    float a = pos * inv;
    float sn, cs;
    __sincosf(a, &sn, &cs);
    p[i]      = f2b((x1 * cs - x2 * sn) * scale);
    p[i + 32] = f2b((x2 * cs + x1 * sn) * scale);
}

// ---------------- causal GQA flash attention v9: 32x32 MFMA, shfl-only cross-lane ----------------
// Same structure as v8 (wave-private dbuf pipeline, sequential band-pair, end merge) but ALL
// cross-lane movement via __shfl/__shfl_xor (certain semantics) — no permlane.
// Lane owns q = l&31; hl = l>>5 selects key/k sub-range. 2 waves split each tile's 64 keys.
__global__ __launch_bounds__(128, 2)
void attn_kernel(const unsigned short* __restrict__ QKV, // [2048][3072] bf16 (q|k|v)
                 const unsigned short* __restrict__ VT,  // [512][2048]  bf16
                 unsigned short* __restrict__ O) {       // [2048][2048] bf16
    const int S = 2048, LDQ = 3072, HID = 2048;
    __shared__ __align__(16) char smem[32768];
    unsigned short* KlBase = (unsigned short*)smem;            // [buf][w][32*64]
    unsigned short* VlBase = (unsigned short*)(smem + 16384);  // [buf][w][64*32]
    float* Ms = (float*)smem;                                  // [64][69], after final barrier

    int tid = threadIdx.x;
    int l = tid & 63, w = tid >> 6;        // 2 waves
    int lq = l & 31, hl = l >> 5;
    int b = blockIdx.x;
    int h = b & 31;
    int pi = b >> 5;                        // 0..31
    int bH = 63 - pi, bL = pi;              // 32-row bands
    int nH = (bH >> 1) + 1;                 // heavy tile count; light = 33-nH
    int kvh = h >> 2;
    int qH = bH * 32 + lq;
    int qL = bL * 32 + lq;

    short8 qfH[4], qfL[4];
    {
        const unsigned short* QrH = QKV + (size_t)qH * LDQ + h * 64;
        const unsigned short* QrL = QKV + (size_t)qL * LDQ + h * 64;
        #pragma unroll
        for (int c = 0; c < 4; ++c) {
            qfH[c] = *reinterpret_cast<const short8*>(QrH + c * 16 + hl * 8);
            qfL[c] = *reinterpret_cast<const short8*>(QrL + c * 16 + hl * 8);
        }
    }

    const unsigned short* Kg = QKV + 2048 + kvh * 64;
    const unsigned short* Vg = VT + (size_t)(kvh * 64) * S;

    // per-wave staging: K [32 key][64 d] (8 slots/row), V [64 d][32 key] (4 slots/row)
    auto stage = [&](int buf, int c0w) {
        unsigned short* Kl = KlBase + (buf * 2 + w) * 2048;
        unsigned short* Vl = VlBase + (buf * 2 + w) * 2048;
        #pragma unroll
        for (int i = 0; i < 4; ++i) {
            int c = l + 64 * i;
            int kr = c >> 3, ks = (c & 7) ^ (kr & 7);
            gload_lds16(Kg + (size_t)(c0w + kr) * LDQ + ks * 8, &Kl[c * 8]);
        }
        #pragma unroll
        for (int i = 0; i < 4; ++i) {
            int c = l + 64 * i;
            int vr = c >> 2, vs = (c & 3) ^ (vr & 3);
            gload_lds16(Vg + (size_t)vr * S + c0w + vs * 8, &Vl[c * 8]);
        }
    };

    floatx16 accH[2], accL[2];
    #pragma unroll
    for (int d = 0; d < 2; ++d) { accH[d] = (floatx16)(0.f); accL[d] = (floatx16)(0.f); }
    float mH = -1e30f, lH = 0.f, mL = -1e30f, lL = 0.f;

    auto process = [&](int buf, int c0w, const short8* qf, int qrow, bool diag,
                       float& m, float& lsum, floatx16* acc) {
        const unsigned short* Kb = KlBase + (buf * 2 + w) * 2048;
        const unsigned short* Vb = VlBase + (buf * 2 + w) * 2048;
        // QK^T: st[r] = S^T[key-local (r&3)+8*(r>>2)+4*hl][q = lq]
        floatx16 st = (floatx16)(0.f);
        __builtin_amdgcn_s_setprio(1);
        #pragma unroll
        for (int dc = 0; dc < 4; ++dc) {
            short8 kf = *reinterpret_cast<const short8*>(
                Kb + lq * 64 + (((dc * 2 + hl) ^ (lq & 7)) * 8));
            st = __builtin_amdgcn_mfma_f32_32x32x16_bf16(kf, qf[dc], st, 0, 0, 0);
        }
        __builtin_amdgcn_s_setprio(0);
        if (diag) {
            #pragma unroll
            for (int r = 0; r < 16; ++r) {
                int key = c0w + (r & 3) + 8 * (r >> 2) + 4 * hl;
                if (key > qrow) st[r] = -1e30f;
            }
        }
        // row-max: local tree + cross-half shfl_xor(32)
        float t0 = fmaxf(fmaxf(st[0], st[1]), fmaxf(st[2], st[3]));
        float t1 = fmaxf(fmaxf(st[4], st[5]), fmaxf(st[6], st[7]));
        float t2 = fmaxf(fmaxf(st[8], st[9]), fmaxf(st[10], st[11]));
        float t3 = fmaxf(fmaxf(st[12], st[13]), fmaxf(st[14], st[15]));
        float tm = fmaxf(fmaxf(t0, t1), fmaxf(t2, t3));
        tm = fmaxf(tm, __shfl_xor(tm, 32));
        if (!__all(tm <= m + 11.5f)) {
            float mn = fmaxf(m, tm);
            float al = exp2_(m - mn);
            lsum *= al;
            acc[0] *= al;
            acc[1] *= al;
            m = mn;
        }
        float p[16];
        #pragma unroll
        for (int r = 0; r < 16; ++r) p[r] = exp2_(st[r] - m);
        float s0 = (p[0] + p[1]) + (p[2] + p[3]);
        float s1 = (p[4] + p[5]) + (p[6] + p[7]);
        float s2 = (p[8] + p[9]) + (p[10] + p[11]);
        float s3 = (p[12] + p[13]) + (p[14] + p[15]);
        float rs = (s0 + s1) + (s2 + s3);
        rs += __shfl_xor(rs, 32);
        lsum += rs;
        // pack P -> bf16: u[B2][j] = keys {8*B2 + 4*hl + 2j, +1}
        unsigned int u[4][2];
        #pragma unroll
        for (int B2 = 0; B2 < 4; ++B2) {
            u[B2][0] = cvt_pk_bf16(p[B2 * 4 + 0], p[B2 * 4 + 1]);
            u[B2][1] = cvt_pk_bf16(p[B2 * 4 + 2], p[B2 * 4 + 3]);
        }
        // PV: two 16-key MFMA steps; B-frag via partner-shfl + select (direction-certain)
        #pragma unroll
        for (int kc = 0; kc < 2; ++kc) {
            unsigned int o0 = u[2 * kc][0],     o1 = u[2 * kc][1];     // keys {16kc+4hl+0,1},{+2,3}
            unsigned int e0 = u[2 * kc + 1][0], e1 = u[2 * kc + 1][1]; // keys {16kc+8+4hl+0,1},{+2,3}
            unsigned int t0 = (unsigned int)__shfl((int)o0, l ^ 32);
            unsigned int t1 = (unsigned int)__shfl((int)o1, l ^ 32);
            unsigned int s0p = (unsigned int)__shfl((int)e0, l ^ 32);
            unsigned int s1p = (unsigned int)__shfl((int)e1, l ^ 32);
            union { unsigned int uu[4]; short8 s8; } pf;
            // lane needs keys {16kc + 8hl + 0..7}
            pf.uu[0] = hl ? s0p : o0;
            pf.uu[1] = hl ? s1p : o1;
            pf.uu[2] = hl ? e0 : t0;
            pf.uu[3] = hl ? e1 : t1;
            __builtin_amdgcn_s_setprio(1);
            #pragma unroll
            for (int d = 0; d < 2; ++d) {
                int row = d * 32 + lq;
                short8 vf = *reinterpret_cast<const short8*>(
                    Vb + row * 32 + (((kc * 2 + hl) ^ (row & 3)) * 8));
                acc[d] = __builtin_amdgcn_mfma_f32_32x32x16_bf16(vf, pf.s8, acc[d], 0, 0, 0);
            }
            __builtin_amdgcn_s_setprio(0);
        }
    };

    stage(0, w * 32);                        // heavy tile 0, this wave's key half
    for (int j = 0; j < 33; ++j) {
        int jn = (j < 32) ? j + 1 : 32;
        int tn = (jn < nH) ? jn : jn - nH;
        stage((j + 1) & 1, tn * 64 + w * 32);
        asm volatile("s_waitcnt vmcnt(8)" ::: "memory");   // current tile's 8 landed
        __builtin_amdgcn_sched_barrier(0);
        int buf = j & 1;
        if (j < nH)
            process(buf, j * 64 + w * 32, qfH, qH, j == nH - 1, mH, lH, accH);
        else
            process(buf, (j - nH) * 64 + w * 32, qfL, qL, j == 32, mL, lL, accL);
    }
    asm volatile("s_waitcnt vmcnt(0)" ::: "memory");
    __syncthreads();   // staging region dead -> safe to alias Ms

    if (w == 1) {
        Ms[l * 69 + 0] = mH; Ms[l * 69 + 1] = lH;
        Ms[l * 69 + 2] = mL; Ms[l * 69 + 3] = lL;
        #pragma unroll
        for (int d = 0; d < 2; ++d)
            #pragma unroll
            for (int r = 0; r < 16; ++r) {
                Ms[l * 69 + 4 + d * 16 + r]  = accH[d][r];
                Ms[l * 69 + 36 + d * 16 + r] = accL[d][r];
            }
    }
    __syncthreads();
    if (w == 0) {
        #pragma unroll
        for (int band = 0; band < 2; ++band) {
            float m0 = band ? mL : mH;
            float l0 = band ? lL : lH;
            const floatx16* acc = band ? accL : accH;
            int moff = band ? 2 : 0;
            int aoff = band ? 36 : 4;
            int qrow = band ? qL : qH;
            float m1 = Ms[l * 69 + moff], l1 = Ms[l * 69 + moff + 1];
            float mm = fmaxf(m0, m1);
            float a0 = exp2_(m0 - mm), a1 = exp2_(m1 - mm);
            float inv = 1.0f / (l0 * a0 + l1 * a1);
            a0 *= inv; a1 *= inv;
            unsigned short* Op = O + (size_t)qrow * HID + h * 64 + hl * 4;
            #pragma unroll
            for (int d = 0; d < 2; ++d)
                #pragma unroll
                for (int g4 = 0; g4 < 4; ++g4) {
                    float v0 = acc[d][g4 * 4 + 0] * a0 + Ms[l * 69 + aoff + d * 16 + g4 * 4 + 0] * a1;
                    float v1 = acc[d][g4 * 4 + 1] * a0 + Ms[l * 69 + aoff + d * 16 + g4 * 4 + 1] * a1;
                    float v2 = acc[d][g4 * 4 + 2] * a0 + Ms[l * 69 + aoff + d * 16 + g4 * 4 + 2] * a1;
                    float v3 = acc[d][g4 * 4 + 3] * a0 + Ms[l * 69 + aoff + d * 16 + g4 * 4 + 3] * a1;
                    unsigned long long pk = (unsigned long long)cvt_pk_bf16(v0, v1)
                                          | ((unsigned long long)cvt_pk_bf16(v2, v3) << 32);
                    *reinterpret_cast<unsigned long long*>(Op + d * 32 + g4 * 8) = pk;
                }
        }
    }
}

extern "C" void kernel_launch(void* const* d_in, const int* in_sizes, int n_in,
                              void* d_out, int out_size, void* d_ws, size_t ws_size,
                              hipStream_t stream) {
    const int S = 2048, HID = 2048, KVD = 512, NQKV = 3072;
    const float* hs = (const float*)d_in[0];
    const float* Wq = (const float*)d_in[1];
    const float* Wk = (const float*)d_in[2];
    const float* Wv = (const float*)d_in[3];
    const float* Wo = (const float*)d_in[4];
    const int* pos  = (const int*)d_in[5];

    char* base = (char*)d_ws;
    auto alloc = [&](size_t bytes) {
        char* r = base;
        base += (bytes + 255) & ~(size_t)255;
        return r;
    };
    unsigned short* hs_b     = (unsigned short*)alloc((size_t)S * HID * 2);
    unsigned short* Wqkv     = (unsigned short*)alloc((size_t)NQKV * HID * 2);
    unsigned short* WoT      = (unsigned short*)alloc((size_t)HID * HID * 2);
    unsigned short* qkv      = (unsigned short*)alloc((size_t)S * NQKV * 2);
    unsigned short* vT       = (unsigned short*)alloc((size_t)KVD * S * 2);
    unsigned short* attn_out = (unsigned short*)alloc((size_t)S * HID * 2);

    cast_kernel<<<(S * HID / 4 + 255) / 256, 256, 0, stream>>>(hs, hs_b, S * HID);

    transpose_to_bf16<float><<<dim3(HID / 64, HID / 64), 256, 0, stream>>>(Wq, Wqkv, HID, HID);
    transpose_to_bf16<float><<<dim3(KVD / 64, HID / 64), 256, 0, stream>>>(Wk, Wqkv + (size_t)2048 * HID, KVD, HID);
    transpose_to_bf16<float><<<dim3(KVD / 64, HID / 64), 256, 0, stream>>>(Wv, Wqkv + (size_t)2560 * HID, KVD, HID);
    transpose_to_bf16<float><<<dim3(HID / 64, HID / 64), 256, 0, stream>>>(Wo, WoT, HID, HID);

    gemm64x128<0><<<dim3(NQKV / 128, S / 64), 256, 0, stream>>>(hs_b, Wqkv, qkv, S, NQKV, HID);

    // Q scaled by (1/8)*log2(e) -> softmax runs in exp2 domain
    rope_kernel<<<(S * 32 * 32) / 256, 256, 0, stream>>>(qkv, pos, 32, NQKV, 0.18033688011112042f);
    rope_kernel<<<(S * 8 * 32) / 256, 256, 0, stream>>>(qkv + 2048, pos, 8, NQKV, 1.0f);

    transpose_to_bf16<unsigned short><<<dim3(KVD / 64, S / 64), 256, 0, stream>>>(qkv + 2560, vT, NQKV, S);

    // attention: 1024 blocks x 2 waves (32 heads x 32 band-pairs)
    attn_kernel<<<1024, 128, 0, stream>>>(qkv, vT, attn_out);

    gemm64x128<1><<<dim3(HID / 128, S / 64), 256, 0, stream>>>(attn_out, WoT, (float*)d_out, S, HID, HID);
}